// Round 9
// baseline (467.139 us; speedup 1.0000x reference)
//
#include <hip/hip_runtime.h>
#include <hip/hip_bf16.h>

#define N_NODES 50000
#define N_EDGES 800000
#define IN_CH   128
#define HID     256
#define OUTC    51
#define CHUNK   128                         // nodes per work item
#define NCH     ((N_NODES + CHUNK - 1) / CHUNK)   // 391

typedef __attribute__((ext_vector_type(8))) short  bf16x8;
typedef __attribute__((ext_vector_type(4))) float  f32x4;
typedef __attribute__((ext_vector_type(4))) unsigned int u32x4;

__device__ __forceinline__ float bf2f(unsigned short u) {
    union { unsigned int i; float f; } v; v.i = ((unsigned int)u) << 16; return v.f;
}
__device__ __forceinline__ unsigned short f2bf(float f) {
    union { float f; unsigned int i; } v; v.f = f;
    unsigned int u = v.i;
    unsigned int r = (u + 0x7fffu + ((u >> 16) & 1u)) >> 16;  // RNE
    return (unsigned short)r;
}
__device__ __forceinline__ unsigned short ldbf(const void* p, long i, int isf) {
    return isf ? f2bf(((const float*)p)[i]) : ((const unsigned short*)p)[i];
}
__device__ __forceinline__ float ldf(const void* p, long i, int isf) {
    return isf ? ((const float*)p)[i] : bf2f(((const unsigned short*)p)[i]);
}
// streaming (non-temporal) edge reads — don't pollute L2
__device__ __forceinline__ void load_edge_nt(const int* __restrict__ ei, int e, int is64,
                                             int* src, int* dst) {
    if (is64) { *src = __builtin_nontemporal_load(ei + 2 * e);
                *dst = __builtin_nontemporal_load(ei + 2 * (N_EDGES + e)); }
    else      { *src = __builtin_nontemporal_load(ei + e);
                *dst = __builtin_nontemporal_load(ei + N_EDGES + e); }
}

#define CURBLK 196  // blocks to zero cursor[50001]

// ---------------- init: zero cursor + queues + dtype probe + int64 detect ----------------
__global__ __launch_bounds__(256) void init_kernel(int* __restrict__ cursor,
                                                   const unsigned int* __restrict__ x0w, int* __restrict__ flags,
                                                   const int* __restrict__ ei) {
    int b = blockIdx.x;
    int tid = threadIdx.x;
    if (b < CURBLK) {
        int t = b * 256 + tid;
        if (t < N_NODES + 1) cursor[t] = 0;
        return;
    }
    if (b == CURBLK) {
        // dtype probe (flags[0]); zero work queues flags[2..13]
        if (tid < 64) {
            unsigned int w = x0w[tid];
            unsigned int ex = (w >> 7) & 0xFFu;
            unsigned long long bm = __ballot(ex >= 0x60u && ex <= 0x90u);
            if (tid == 0) flags[0] = (__popcll(bm) >= 48) ? 0 : 1;
        } else if (tid >= 64 && tid < 76) {
            flags[2 + tid - 64] = 0;
        }
        return;
    }
    // int64 detect -> flags[1]: 2048 strided samples of odd words; all-zero => int64
    __shared__ int any;
    if (tid == 0) any = 0;
    __syncthreads();
    int acc = 0;
    for (int s = 0; s < 8; s++) {
        int i = (tid * 8 + s) * (N_EDGES / 2048);
        acc |= ei[2 * i + 1];
    }
    if (acc != 0) any = 1;
    __syncthreads();
    if (tid == 0) flags[1] = any;
}

// ---------------- prep_all: x0 convert (cb blocks) + weight prep ----------------
__global__ void prep_all_kernel(const void* __restrict__ x0, int cb,
                                const void* __restrict__ w1r, const void* __restrict__ w1x,
                                const void* __restrict__ w2r, const void* __restrict__ w2x,
                                const void* __restrict__ lw,
                                const void* __restrict__ b1h, const void* __restrict__ b2h,
                                const void* __restrict__ lbh, const int* __restrict__ flagF,
                                unsigned short* __restrict__ x0bf,
                                unsigned short* __restrict__ Bt1, unsigned short* __restrict__ Bt2,
                                unsigned short* __restrict__ Bt3,
                                float* __restrict__ b1, float* __restrict__ b2, float* __restrict__ b3) {
    int isf = *flagF;
    if ((int)blockIdx.x < cb) {
        long t = (long)blockIdx.x * 256 + threadIdx.x;
        if (t < (long)N_NODES * IN_CH) x0bf[t] = ldbf(x0, t, isf);
        return;
    }
    int t = (blockIdx.x - cb) * 256 + threadIdx.x;
    if (t < 256 * 256) {
        int n = t >> 8, k = t & 255;
        Bt1[n * 256 + k] = (k < 128) ? ldbf(w1r, k * 256 + n, isf) : ldbf(w1x, (k - 128) * 256 + n, isf);
        return;
    }
    t -= 256 * 256;
    if (t < 256 * 512) {
        int n = t >> 9, k = t & 511;
        Bt2[n * 512 + k] = (k < 256) ? ldbf(w2r, k * 256 + n, isf) : ldbf(w2x, (k - 256) * 256 + n, isf);
        return;
    }
    t -= 256 * 512;
    if (t < 64 * 512) {
        int n = t >> 9, k = t & 511;
        Bt3[n * 512 + k] = (n < OUTC) ? ldbf(lw, k * OUTC + n, isf) : (unsigned short)0;
        return;
    }
    t -= 64 * 512;
    if (t < 256) { b1[t] = ldf(b1h, t, isf); return; }
    t -= 256;
    if (t < 256) { b2[t] = ldf(b2h, t, isf); return; }
    t -= 256;
    if (t < 64)  { b3[t] = (t < OUTC) ? ldf(lbh, t, isf) : 0.0f; return; }
}

// ---------------- CSR: histogram ----------------
__global__ __launch_bounds__(256) void hist_kernel(const int* __restrict__ ei, const int* __restrict__ flagI,
                                                   int* __restrict__ cnt) {
    int e = blockIdx.x * 256 + threadIdx.x;
    if (e >= N_EDGES) return;
    int is64 = (*flagI == 0);
    int src, dst; load_edge_nt(ei, e, is64, &src, &dst);
    if ((unsigned)src >= N_NODES || (unsigned)dst >= N_NODES) return;
    atomicAdd(&cnt[dst], 1);
}

// ---------------- scan A: per-block exclusive + block sums ----------------
__global__ __launch_bounds__(256) void scanA_kernel(const int* __restrict__ cnt, int* __restrict__ rp,
                                                    int* __restrict__ bsum) {
    __shared__ int sd[256];
    int tid = threadIdx.x;
    int i = blockIdx.x * 256 + tid;
    int v = (i < N_NODES) ? cnt[i] : 0;
    sd[tid] = v;
    __syncthreads();
    for (int off = 1; off < 256; off <<= 1) {
        int t = (tid >= off) ? sd[tid - off] : 0;
        __syncthreads();
        sd[tid] += t;
        __syncthreads();
    }
    if (i < N_NODES) rp[i] = sd[tid] - v;
    if (tid == 255) bsum[blockIdx.x] = sd[255];
}
// ---------------- scan C: re-scan bsum locally, apply prefix ----------------
__global__ __launch_bounds__(256) void scanC_kernel(int* __restrict__ rp, const int* __restrict__ bsum,
                                                    int* __restrict__ cursor, int nB) {
    __shared__ int sd[256];
    int tid = threadIdx.x;
    int v = (tid < nB) ? bsum[tid] : 0;
    sd[tid] = v;
    __syncthreads();
    for (int off = 1; off < 256; off <<= 1) {
        int t = (tid >= off) ? sd[tid - off] : 0;
        __syncthreads();
        sd[tid] += t;
        __syncthreads();
    }
    int pfx = (blockIdx.x > 0) ? sd[blockIdx.x - 1] : 0;
    int i = blockIdx.x * 256 + tid;
    if (i < N_NODES) {
        int val = rp[i] + pfx;
        rp[i] = val;
        cursor[i] = val;
    }
    if (blockIdx.x == 0 && tid == 0) rp[N_NODES] = sd[255];
}

// ---------------- CSR: fill — one packed 4B record per edge ----------------
// cw[pos] = (wgt_bf16 << 16) | src   (src < 50000 < 2^16)
__global__ __launch_bounds__(256) void fill_kernel(const int* __restrict__ ei, const void* __restrict__ ew,
                                                   const int* __restrict__ flagI, const int* __restrict__ flagF,
                                                   int* __restrict__ cursor, unsigned int* __restrict__ cw) {
    int e = blockIdx.x * 256 + threadIdx.x;
    if (e >= N_EDGES) return;
    int is64 = (*flagI == 0);
    int src, dst; load_edge_nt(ei, e, is64, &src, &dst);
    if ((unsigned)src >= N_NODES || (unsigned)dst >= N_NODES) return;
    int pos = atomicAdd(&cursor[dst], 1);
    if ((unsigned)pos < N_EDGES)
        cw[pos] = ((unsigned int)ldbf(ew, e, *flagF) << 16) | (unsigned int)src;
}

// ---------------- fallback: zero output ----------------
__global__ __launch_bounds__(256) void zout_kernel(unsigned short* __restrict__ out, long n) {
    long t = (long)blockIdx.x * 256 + threadIdx.x;
    if (t < n) out[t] = 0;
}

// ---------------- XCD-pinned sliced aggregation ----------------
// True XCD affinity via s_getreg(HW_REG_XCC_ID): block claims (slice=own XCD,
// chunk) from per-slice atomic queues; steals cross-XCD only on imbalance.
// Slice = 32 channels (64B/row) -> per-XCD gather working set 3.2 MB (L2-fits).
// 8-lane groups, 8B/lane: one full 64B line per edge; 8 loads in flight.
template<int SLICES>
__global__ __launch_bounds__(256) void agg_kernel(const unsigned short* __restrict__ gx, int gstride,
                                                  const int* __restrict__ rp, const unsigned int* __restrict__ cw,
                                                  unsigned short* __restrict__ X12, int* __restrict__ q) {
    __shared__ int ssl, sck;
    int tid = threadIdx.x;
    if (tid == 0) {
        unsigned int x;
        asm volatile("s_getreg_b32 %0, hwreg(HW_REG_XCC_ID)" : "=s"(x));
        int pref = (int)(x & (SLICES - 1));
        int sl = -1, ck = -1;
        for (int t = 0; t < SLICES; t++) {
            int s = (pref + t) & (SLICES - 1);
            int i = atomicAdd(&q[s], 1);
            if (i < NCH) { sl = s; ck = i; break; }
        }
        ssl = sl; sck = ck;
    }
    __syncthreads();
    int sl = ssl;
    if (sl < 0) return;
    int r0 = sck * CHUNK;
    int rend = r0 + CHUNK; if (rend > N_NODES) rend = N_NODES;
    int l = tid & 7;
    int grp = tid >> 3;          // 32 groups/block
    int grpbase = tid & 56;      // group base lane within the 64-lane wave
    const unsigned short* xc = gx + sl * 32 + l * 4;

    for (int r = r0 + grp; r < rend; r += 32) {
        int js = rp[r], je = rp[r + 1];
        if (js < 0) js = 0;
        if (je > N_EDGES) je = N_EDGES;
        float a0 = 0.f, a1 = 0.f, a2 = 0.f, a3 = 0.f;
        for (int base = js; base < je; base += 8) {
            int n = je - base; if (n > 8) n = 8;
            int idx = base + l; if (idx >= je) idx = je - 1;
            unsigned int rec = __builtin_nontemporal_load(cw + idx);
            unsigned int vv[8]; uint2 qd[8];
#pragma unroll
            for (int u = 0; u < 8; u++) vv[u] = __shfl(rec, grpbase + u);
#pragma unroll
            for (int u = 0; u < 8; u++) if (u < n)
                qd[u] = *(const uint2*)(xc + (long)(vv[u] & 0xFFFFu) * gstride);
#pragma unroll
            for (int u = 0; u < 8; u++) if (u < n) {
                float w = bf2f((unsigned short)(vv[u] >> 16));
                a0 += w * bf2f((unsigned short)(qd[u].x & 0xffffu));
                a1 += w * bf2f((unsigned short)(qd[u].x >> 16));
                a2 += w * bf2f((unsigned short)(qd[u].y & 0xffffu));
                a3 += w * bf2f((unsigned short)(qd[u].y >> 16));
            }
        }
        uint2 pk;
        pk.x = (unsigned int)f2bf(a0) | ((unsigned int)f2bf(a1) << 16);
        pk.y = (unsigned int)f2bf(a2) | ((unsigned int)f2bf(a3) << 16);
        *(uint2*)&X12[(long)r * 512 + 256 + sl * 32 + l * 4] = pk;
    }
}

// ---------------- MFMA GEMM, full-width (grid y=1) -------------------
template<int TN>
__global__ __launch_bounds__(256) void gemm_kernel(
    const unsigned short* __restrict__ Aagg, int lda_agg, int Kagg,
    const unsigned short* __restrict__ Ax, int lda_x,
    const unsigned short* __restrict__ Bt, int K,
    const float* __restrict__ bias,
    void* __restrict__ out, int ldo, int ocol,
    int M, int realN, int do_relu, const int* __restrict__ flagF, int follow_dtype) {
    __shared__ __align__(16) unsigned short As[64][72];
    __shared__ __align__(16) unsigned short Bs[TN * 32][72];
    int tid = threadIdx.x;
    int bm0 = blockIdx.x * 64;
    int wave = tid >> 6, lane = tid & 63;
    int wm = wave >> 1, wn = wave & 1;
    int quad = lane >> 4, l16 = lane & 15;

    f32x4 acc[2][TN];
#pragma unroll
    for (int mt = 0; mt < 2; mt++)
#pragma unroll
        for (int nt = 0; nt < TN; nt++) acc[mt][nt] = (f32x4){0.f, 0.f, 0.f, 0.f};

    for (int k0 = 0; k0 < K; k0 += 64) {
        const unsigned short* srcp;
        int stride, koff;
        if (k0 < Kagg) { srcp = Aagg; stride = lda_agg; koff = k0; }
        else           { srcp = Ax;   stride = lda_x;   koff = k0 - Kagg; }
#pragma unroll
        for (int i = 0; i < 2; i++) {
            int c = tid + i * 256;
            int row = c >> 3, ko = (c & 7) * 8;
            int gr = bm0 + row;
            if (gr >= M) gr = M - 1;  // clamp: dup rows, writes guarded
            u32x4 v = *(const u32x4*)(srcp + (long)gr * stride + koff + ko);
            *(u32x4*)&As[row][ko] = v;
        }
#pragma unroll
        for (int p = 0; p < TN; p++) {
            int c = p * 256 + tid;
            int row = c >> 3, ko = (c & 7) * 8;
            u32x4 v = *(const u32x4*)(Bt + (long)row * K + k0 + ko);
            *(u32x4*)&Bs[row][ko] = v;
        }
        __syncthreads();
#pragma unroll
        for (int kc = 0; kc < 64; kc += 32) {
            bf16x8 a0 = *(const bf16x8*)&As[wm * 32 + l16][kc + quad * 8];
            bf16x8 a1 = *(const bf16x8*)&As[wm * 32 + 16 + l16][kc + quad * 8];
#pragma unroll
            for (int nt = 0; nt < TN; nt++) {
                bf16x8 b = *(const bf16x8*)&Bs[wn * (TN * 16) + nt * 16 + l16][kc + quad * 8];
                acc[0][nt] = __builtin_amdgcn_mfma_f32_16x16x32_bf16(a0, b, acc[0][nt], 0, 0, 0);
                acc[1][nt] = __builtin_amdgcn_mfma_f32_16x16x32_bf16(a1, b, acc[1][nt], 0, 0, 0);
            }
        }
        __syncthreads();
    }

    int out_f32 = follow_dtype ? (*flagF) : 0;
#pragma unroll
    for (int mt = 0; mt < 2; mt++) {
#pragma unroll
        for (int nt = 0; nt < TN; nt++) {
            f32x4 a = acc[mt][nt];
            int colI = wn * (TN * 16) + nt * 16 + l16;
            float bv = bias[colI];
#pragma unroll
            for (int r = 0; r < 4; r++) {
                int row = bm0 + wm * 32 + mt * 16 + quad * 4 + r;
                if (row < M && colI < realN) {
                    float v = a[r] + bv;
                    if (do_relu) v = v > 0.f ? v : 0.f;
                    long idx = (long)row * ldo + ocol + colI;
                    if (out_f32) ((float*)out)[idx] = v;
                    else ((unsigned short*)out)[idx] = f2bf(v);
                }
            }
        }
    }
}

extern "C" void kernel_launch(void* const* d_in, const int* in_sizes, int n_in,
                              void* d_out, int out_size, void* d_ws, size_t ws_size,
                              hipStream_t stream) {
    const void* x0  = d_in[0];
    const int*  ei  = (const int*)d_in[1];
    const void* ew  = d_in[2];
    const void* w1r = d_in[3];
    const void* b1h = d_in[4];
    const void* w1x = d_in[5];
    const void* w2r = d_in[6];
    const void* b2h = d_in[7];
    const void* w2x = d_in[8];
    const void* lw  = d_in[9];
    const void* lbh = d_in[10];

    // ---- workspace layout ----
    char* ws = (char*)d_ws;
    unsigned short* X12     = (unsigned short*)(ws);             // 51,200,000  [N x 512]
    unsigned int*   cw      = (unsigned int*)(ws + 51200000);    //  3,200,000  packed (wgt<<16|src)
    int*            row_ptr = (int*)(ws + 54400000);             //    200,064
    int*            cursor  = (int*)(ws + 54600064);             //    200,064
    unsigned short* Bt1     = (unsigned short*)(ws + 54800128);  //    131,072
    unsigned short* Bt2     = (unsigned short*)(ws + 54931200);  //    262,144
    unsigned short* Bt3     = (unsigned short*)(ws + 55193344);  //     65,536
    float*          b1      = (float*)(ws + 55258880);           //      1,024
    float*          b2      = (float*)(ws + 55259904);           //      1,024
    float*          b3      = (float*)(ws + 55260928);           //        256
    int*            flags   = (int*)(ws + 55261184);             //         64 (flagF, flagI, q1[4], q2[8])
    int*            bsum    = (int*)(ws + 55261248);             //      1,024
    unsigned short* x0bf    = (unsigned short*)(ws + 55262272);  // 12,800,000
    const size_t NEED_FULL   = 68062272;
    const size_t NEED_NOCONV = 55262272;

    if (ws_size < NEED_NOCONV) {
        long n = (long)N_NODES * OUTC;
        zout_kernel<<<(int)((n + 255) / 256), 256, 0, stream>>>((unsigned short*)d_out, n);
        return;
    }
    int do_conv = (ws_size >= NEED_FULL) ? 1 : 0;

    int* flagF = flags + 0;
    int* flagI = flags + 1;
    int* q1    = flags + 2;  // 4 counters (agg1)
    int* q2    = flags + 6;  // 8 counters (agg2)

    init_kernel<<<CURBLK + 2, 256, 0, stream>>>(cursor, (const unsigned int*)x0, flags, ei);

    int cb = do_conv ? ((N_NODES * IN_CH + 255) / 256) : 0;  // 25000
    const unsigned short* x0b = do_conv ? x0bf : (const unsigned short*)x0;
    {
        int ptotal = 256 * 256 + 256 * 512 + 64 * 512 + 256 + 256 + 64;
        int pblocks = (ptotal + 255) / 256;  // 899
        prep_all_kernel<<<cb + pblocks, 256, 0, stream>>>(x0, cb, w1r, w1x, w2r, w2x, lw,
                                                          b1h, b2h, lbh, flagF, x0bf,
                                                          Bt1, Bt2, Bt3, b1, b2, b3);
    }

    // CSR build
    int eblocks = (N_EDGES + 255) / 256;
    int nblk = (N_NODES + 255) / 256;  // 196
    hist_kernel<<<eblocks, 256, 0, stream>>>(ei, flagI, cursor);
    scanA_kernel<<<nblk, 256, 0, stream>>>(cursor, row_ptr, bsum);
    scanC_kernel<<<nblk, 256, 0, stream>>>(row_ptr, bsum, cursor, nblk);
    fill_kernel<<<eblocks, 256, 0, stream>>>(ei, ew, flagI, flagF, cursor, cw);

    int mblocks = (N_NODES + 63) / 64;   // 782

    // layer 1: agg over x0 (128 ch = 4 slices, XCD-pinned) -> X12 cols 256..383
    agg_kernel<4><<<4 * NCH, 256, 0, stream>>>(x0b, IN_CH, row_ptr, cw, X12, q1);
    gemm_kernel<8><<<dim3(mblocks, 1), 256, 0, stream>>>(X12 + 256, 512, 128,
                                                         x0b, IN_CH, Bt1, 256, b1,
                                                         X12, 512, 0, N_NODES, 256, 1, flagF, 0);
    // layer 2: agg over x1 (256 ch = 8 slices, XCD-pinned) -> X12 cols 256..511
    agg_kernel<8><<<8 * NCH, 256, 0, stream>>>(X12, 512, row_ptr, cw, X12, q2);
    gemm_kernel<8><<<dim3(mblocks, 1), 256, 0, stream>>>(X12 + 256, 512, 256,
                                                         X12, 512, Bt2, 512, b2,
                                                         X12, 512, 256, N_NODES, 256, 1, flagF, 0);
    // head: [x1|x2] @ Bt3 -> out
    gemm_kernel<2><<<dim3(mblocks, 1), 256, 0, stream>>>(X12 + 256, 512, 0,
                                                         X12, 512, Bt3, 512, b3,
                                                         d_out, OUTC, 0, N_NODES, OUTC, 0, flagF, 1);
}

// Round 10
// 373.457 us; speedup vs baseline: 1.2509x; 1.2509x over previous
//
#include <hip/hip_runtime.h>
#include <hip/hip_bf16.h>

#define N_NODES 50000
#define N_EDGES 800000
#define IN_CH   128
#define HID     256
#define OUTC    51

typedef __attribute__((ext_vector_type(8))) short  bf16x8;
typedef __attribute__((ext_vector_type(4))) float  f32x4;
typedef __attribute__((ext_vector_type(4))) unsigned int u32x4;

__device__ __forceinline__ float bf2f(unsigned short u) {
    union { unsigned int i; float f; } v; v.i = ((unsigned int)u) << 16; return v.f;
}
__device__ __forceinline__ unsigned short f2bf(float f) {
    union { float f; unsigned int i; } v; v.f = f;
    unsigned int u = v.i;
    unsigned int r = (u + 0x7fffu + ((u >> 16) & 1u)) >> 16;  // RNE
    return (unsigned short)r;
}
__device__ __forceinline__ unsigned short ldbf(const void* p, long i, int isf) {
    return isf ? f2bf(((const float*)p)[i]) : ((const unsigned short*)p)[i];
}
__device__ __forceinline__ float ldf(const void* p, long i, int isf) {
    return isf ? ((const float*)p)[i] : bf2f(((const unsigned short*)p)[i]);
}
// streaming (non-temporal) edge reads — don't pollute L2
__device__ __forceinline__ void load_edge_nt(const int* __restrict__ ei, int e, int is64,
                                             int* src, int* dst) {
    if (is64) { *src = __builtin_nontemporal_load(ei + 2 * e);
                *dst = __builtin_nontemporal_load(ei + 2 * (N_EDGES + e)); }
    else      { *src = __builtin_nontemporal_load(ei + e);
                *dst = __builtin_nontemporal_load(ei + N_EDGES + e); }
}

#define CURBLK 196  // blocks to zero cursor[50001]

// ---------------- init: zero cursor + dtype probe + int64 detect ----------------
__global__ __launch_bounds__(256) void init_kernel(int* __restrict__ cursor,
                                                   const unsigned int* __restrict__ x0w, int* __restrict__ flags,
                                                   const int* __restrict__ ei) {
    int b = blockIdx.x;
    int tid = threadIdx.x;
    if (b < CURBLK) {
        int t = b * 256 + tid;
        if (t < N_NODES + 1) cursor[t] = 0;
        return;
    }
    if (b == CURBLK) {
        if (tid < 64) {
            unsigned int w = x0w[tid];
            unsigned int ex = (w >> 7) & 0xFFu;
            unsigned long long bm = __ballot(ex >= 0x60u && ex <= 0x90u);
            if (tid == 0) flags[0] = (__popcll(bm) >= 48) ? 0 : 1;
        }
        return;
    }
    // int64 detect -> flags[1]: 2048 strided samples of odd words; all-zero => int64
    __shared__ int any;
    if (tid == 0) any = 0;
    __syncthreads();
    int acc = 0;
    for (int s = 0; s < 8; s++) {
        int i = (tid * 8 + s) * (N_EDGES / 2048);
        acc |= ei[2 * i + 1];
    }
    if (acc != 0) any = 1;
    __syncthreads();
    if (tid == 0) flags[1] = any;
}

// ---------------- prep_all: x0 convert (cb blocks) + weight prep ----------------
__global__ void prep_all_kernel(const void* __restrict__ x0, int cb,
                                const void* __restrict__ w1r, const void* __restrict__ w1x,
                                const void* __restrict__ w2r, const void* __restrict__ w2x,
                                const void* __restrict__ lw,
                                const void* __restrict__ b1h, const void* __restrict__ b2h,
                                const void* __restrict__ lbh, const int* __restrict__ flagF,
                                unsigned short* __restrict__ x0bf,
                                unsigned short* __restrict__ Bt1, unsigned short* __restrict__ Bt2,
                                unsigned short* __restrict__ Bt3,
                                float* __restrict__ b1, float* __restrict__ b2, float* __restrict__ b3) {
    int isf = *flagF;
    if ((int)blockIdx.x < cb) {
        long t = (long)blockIdx.x * 256 + threadIdx.x;
        if (t < (long)N_NODES * IN_CH) x0bf[t] = ldbf(x0, t, isf);
        return;
    }
    int t = (blockIdx.x - cb) * 256 + threadIdx.x;
    if (t < 256 * 256) {
        int n = t >> 8, k = t & 255;
        Bt1[n * 256 + k] = (k < 128) ? ldbf(w1r, k * 256 + n, isf) : ldbf(w1x, (k - 128) * 256 + n, isf);
        return;
    }
    t -= 256 * 256;
    if (t < 256 * 512) {
        int n = t >> 9, k = t & 511;
        Bt2[n * 512 + k] = (k < 256) ? ldbf(w2r, k * 256 + n, isf) : ldbf(w2x, (k - 256) * 256 + n, isf);
        return;
    }
    t -= 256 * 512;
    if (t < 64 * 512) {
        int n = t >> 9, k = t & 511;
        Bt3[n * 512 + k] = (n < OUTC) ? ldbf(lw, k * OUTC + n, isf) : (unsigned short)0;
        return;
    }
    t -= 64 * 512;
    if (t < 256) { b1[t] = ldf(b1h, t, isf); return; }
    t -= 256;
    if (t < 256) { b2[t] = ldf(b2h, t, isf); return; }
    t -= 256;
    if (t < 64)  { b3[t] = (t < OUTC) ? ldf(lbh, t, isf) : 0.0f; return; }
}

// ---------------- CSR: histogram ----------------
__global__ __launch_bounds__(256) void hist_kernel(const int* __restrict__ ei, const int* __restrict__ flagI,
                                                   int* __restrict__ cnt) {
    int e = blockIdx.x * 256 + threadIdx.x;
    if (e >= N_EDGES) return;
    int is64 = (*flagI == 0);
    int src, dst; load_edge_nt(ei, e, is64, &src, &dst);
    if ((unsigned)src >= N_NODES || (unsigned)dst >= N_NODES) return;
    atomicAdd(&cnt[dst], 1);
}

// ---------------- scan A: per-block exclusive + block sums ----------------
__global__ __launch_bounds__(256) void scanA_kernel(const int* __restrict__ cnt, int* __restrict__ rp,
                                                    int* __restrict__ bsum) {
    __shared__ int sd[256];
    int tid = threadIdx.x;
    int i = blockIdx.x * 256 + tid;
    int v = (i < N_NODES) ? cnt[i] : 0;
    sd[tid] = v;
    __syncthreads();
    for (int off = 1; off < 256; off <<= 1) {
        int t = (tid >= off) ? sd[tid - off] : 0;
        __syncthreads();
        sd[tid] += t;
        __syncthreads();
    }
    if (i < N_NODES) rp[i] = sd[tid] - v;
    if (tid == 255) bsum[blockIdx.x] = sd[255];
}
// ---------------- scan C: re-scan bsum locally, apply prefix ----------------
__global__ __launch_bounds__(256) void scanC_kernel(int* __restrict__ rp, const int* __restrict__ bsum,
                                                    int* __restrict__ cursor, int nB) {
    __shared__ int sd[256];
    int tid = threadIdx.x;
    int v = (tid < nB) ? bsum[tid] : 0;
    sd[tid] = v;
    __syncthreads();
    for (int off = 1; off < 256; off <<= 1) {
        int t = (tid >= off) ? sd[tid - off] : 0;
        __syncthreads();
        sd[tid] += t;
        __syncthreads();
    }
    int pfx = (blockIdx.x > 0) ? sd[blockIdx.x - 1] : 0;
    int i = blockIdx.x * 256 + tid;
    if (i < N_NODES) {
        int val = rp[i] + pfx;
        rp[i] = val;
        cursor[i] = val;
    }
    if (blockIdx.x == 0 && tid == 0) rp[N_NODES] = sd[255];
}

// ---------------- CSR: fill — one packed 4B record per edge ----------------
// cw[pos] = (wgt_bf16 << 16) | src   (src < 50000 < 2^16)
__global__ __launch_bounds__(256) void fill_kernel(const int* __restrict__ ei, const void* __restrict__ ew,
                                                   const int* __restrict__ flagI, const int* __restrict__ flagF,
                                                   int* __restrict__ cursor, unsigned int* __restrict__ cw) {
    int e = blockIdx.x * 256 + threadIdx.x;
    if (e >= N_EDGES) return;
    int is64 = (*flagI == 0);
    int src, dst; load_edge_nt(ei, e, is64, &src, &dst);
    if ((unsigned)src >= N_NODES || (unsigned)dst >= N_NODES) return;
    int pos = atomicAdd(&cursor[dst], 1);
    if ((unsigned)pos < N_EDGES)
        cw[pos] = ((unsigned int)ldbf(ew, e, *flagF) << 16) | (unsigned int)src;
}

// ---------------- fallback: zero output ----------------
__global__ __launch_bounds__(256) void zout_kernel(unsigned short* __restrict__ out, long n) {
    long t = (long)blockIdx.x * 256 + threadIdx.x;
    if (t < n) out[t] = 0;
}

// ---------------- agg1: X12[r][256+c] = bf16(sum_j w_j * x0[src_j][c]), c<128 ----------------
// wave per node (r7-best shape); packed cw: 1 nt-load per edge; 8 row-loads in flight
__global__ __launch_bounds__(256) void agg1_kernel(const unsigned short* __restrict__ x0b,
                                                   const int* __restrict__ rp, const unsigned int* __restrict__ cw,
                                                   unsigned short* __restrict__ X12) {
    int r = blockIdx.x * 4 + (threadIdx.x >> 6);
    if (r >= N_NODES) return;
    int lane = threadIdx.x & 63;
    int js = rp[r], je = rp[r + 1];
    if (js < 0) js = 0;
    if (je > N_EDGES) je = N_EDGES;
    const unsigned int* xw = (const unsigned int*)x0b;  // 64 uints per row
    float a0 = 0.f, a1 = 0.f;
    for (int base = js; base < je; base += 64) {
        int n = je - base; if (n > 64) n = 64;
        int idx = base + lane; if (idx >= N_EDGES) idx = N_EDGES - 1;
        unsigned int rec = __builtin_nontemporal_load(cw + idx);
        for (int j = 0; j < n; j += 8) {
            int m = n - j; if (m > 8) m = 8;
            unsigned int vv[8], q[8];
#pragma unroll
            for (int u = 0; u < 8; u++) vv[u] = __shfl(rec, j + u);
#pragma unroll
            for (int u = 0; u < 8; u++) if (u < m)
                q[u] = xw[(long)(vv[u] & 0xFFFFu) * 64 + lane];
#pragma unroll
            for (int u = 0; u < 8; u++) if (u < m) {
                float w = bf2f((unsigned short)(vv[u] >> 16));
                a0 += w * bf2f((unsigned short)(q[u] & 0xffffu));
                a1 += w * bf2f((unsigned short)(q[u] >> 16));
            }
        }
    }
    unsigned int pk = (unsigned int)f2bf(a0) | ((unsigned int)f2bf(a1) << 16);
    *(unsigned int*)&X12[(long)r * 512 + 256 + lane * 2] = pk;
}

// ---------------- agg2: X12[r][256+c] = bf16(sum_j w_j * x1[src_j][c]), c<256 ----------------
// x1 = X12 cols 0..255; writes cols 256..511
__global__ __launch_bounds__(256) void agg2_kernel(const int* __restrict__ rp, const unsigned int* __restrict__ cw,
                                                   unsigned short* __restrict__ X12) {
    int r = blockIdx.x * 4 + (threadIdx.x >> 6);
    if (r >= N_NODES) return;
    int lane = threadIdx.x & 63;
    int js = rp[r], je = rp[r + 1];
    if (js < 0) js = 0;
    if (je > N_EDGES) je = N_EDGES;
    float a0 = 0.f, a1 = 0.f, a2 = 0.f, a3 = 0.f;
    for (int base = js; base < je; base += 64) {
        int n = je - base; if (n > 64) n = 64;
        int idx = base + lane; if (idx >= N_EDGES) idx = N_EDGES - 1;
        unsigned int rec = __builtin_nontemporal_load(cw + idx);
        for (int j = 0; j < n; j += 8) {
            int m = n - j; if (m > 8) m = 8;
            unsigned int vv[8]; uint2 q[8];
#pragma unroll
            for (int u = 0; u < 8; u++) vv[u] = __shfl(rec, j + u);
#pragma unroll
            for (int u = 0; u < 8; u++) if (u < m)
                q[u] = *(const uint2*)(X12 + (long)(vv[u] & 0xFFFFu) * 512 + lane * 4);
#pragma unroll
            for (int u = 0; u < 8; u++) if (u < m) {
                float w = bf2f((unsigned short)(vv[u] >> 16));
                a0 += w * bf2f((unsigned short)(q[u].x & 0xffffu));
                a1 += w * bf2f((unsigned short)(q[u].x >> 16));
                a2 += w * bf2f((unsigned short)(q[u].y & 0xffffu));
                a3 += w * bf2f((unsigned short)(q[u].y >> 16));
            }
        }
    }
    uint2 pk;
    pk.x = (unsigned int)f2bf(a0) | ((unsigned int)f2bf(a1) << 16);
    pk.y = (unsigned int)f2bf(a2) | ((unsigned int)f2bf(a3) << 16);
    *(uint2*)&X12[(long)r * 512 + 256 + lane * 4] = pk;
}

// ---------------- MFMA GEMM, full-width (grid y=1) -------------------
template<int TN>
__global__ __launch_bounds__(256) void gemm_kernel(
    const unsigned short* __restrict__ Aagg, int lda_agg, int Kagg,
    const unsigned short* __restrict__ Ax, int lda_x,
    const unsigned short* __restrict__ Bt, int K,
    const float* __restrict__ bias,
    void* __restrict__ out, int ldo, int ocol,
    int M, int realN, int do_relu, const int* __restrict__ flagF, int follow_dtype) {
    __shared__ __align__(16) unsigned short As[64][72];
    __shared__ __align__(16) unsigned short Bs[TN * 32][72];
    int tid = threadIdx.x;
    int bm0 = blockIdx.x * 64;
    int wave = tid >> 6, lane = tid & 63;
    int wm = wave >> 1, wn = wave & 1;
    int quad = lane >> 4, l16 = lane & 15;

    f32x4 acc[2][TN];
#pragma unroll
    for (int mt = 0; mt < 2; mt++)
#pragma unroll
        for (int nt = 0; nt < TN; nt++) acc[mt][nt] = (f32x4){0.f, 0.f, 0.f, 0.f};

    for (int k0 = 0; k0 < K; k0 += 64) {
        const unsigned short* srcp;
        int stride, koff;
        if (k0 < Kagg) { srcp = Aagg; stride = lda_agg; koff = k0; }
        else           { srcp = Ax;   stride = lda_x;   koff = k0 - Kagg; }
#pragma unroll
        for (int i = 0; i < 2; i++) {
            int c = tid + i * 256;
            int row = c >> 3, ko = (c & 7) * 8;
            int gr = bm0 + row;
            if (gr >= M) gr = M - 1;  // clamp: dup rows, writes guarded
            u32x4 v = *(const u32x4*)(srcp + (long)gr * stride + koff + ko);
            *(u32x4*)&As[row][ko] = v;
        }
#pragma unroll
        for (int p = 0; p < TN; p++) {
            int c = p * 256 + tid;
            int row = c >> 3, ko = (c & 7) * 8;
            u32x4 v = *(const u32x4*)(Bt + (long)row * K + k0 + ko);
            *(u32x4*)&Bs[row][ko] = v;
        }
        __syncthreads();
#pragma unroll
        for (int kc = 0; kc < 64; kc += 32) {
            bf16x8 a0 = *(const bf16x8*)&As[wm * 32 + l16][kc + quad * 8];
            bf16x8 a1 = *(const bf16x8*)&As[wm * 32 + 16 + l16][kc + quad * 8];
#pragma unroll
            for (int nt = 0; nt < TN; nt++) {
                bf16x8 b = *(const bf16x8*)&Bs[wn * (TN * 16) + nt * 16 + l16][kc + quad * 8];
                acc[0][nt] = __builtin_amdgcn_mfma_f32_16x16x32_bf16(a0, b, acc[0][nt], 0, 0, 0);
                acc[1][nt] = __builtin_amdgcn_mfma_f32_16x16x32_bf16(a1, b, acc[1][nt], 0, 0, 0);
            }
        }
        __syncthreads();
    }

    int out_f32 = follow_dtype ? (*flagF) : 0;
#pragma unroll
    for (int mt = 0; mt < 2; mt++) {
#pragma unroll
        for (int nt = 0; nt < TN; nt++) {
            f32x4 a = acc[mt][nt];
            int colI = wn * (TN * 16) + nt * 16 + l16;
            float bv = bias[colI];
#pragma unroll
            for (int r = 0; r < 4; r++) {
                int row = bm0 + wm * 32 + mt * 16 + quad * 4 + r;
                if (row < M && colI < realN) {
                    float v = a[r] + bv;
                    if (do_relu) v = v > 0.f ? v : 0.f;
                    long idx = (long)row * ldo + ocol + colI;
                    if (out_f32) ((float*)out)[idx] = v;
                    else ((unsigned short*)out)[idx] = f2bf(v);
                }
            }
        }
    }
}

extern "C" void kernel_launch(void* const* d_in, const int* in_sizes, int n_in,
                              void* d_out, int out_size, void* d_ws, size_t ws_size,
                              hipStream_t stream) {
    const void* x0  = d_in[0];
    const int*  ei  = (const int*)d_in[1];
    const void* ew  = d_in[2];
    const void* w1r = d_in[3];
    const void* b1h = d_in[4];
    const void* w1x = d_in[5];
    const void* w2r = d_in[6];
    const void* b2h = d_in[7];
    const void* w2x = d_in[8];
    const void* lw  = d_in[9];
    const void* lbh = d_in[10];

    // ---- workspace layout ----
    char* ws = (char*)d_ws;
    unsigned short* X12     = (unsigned short*)(ws);             // 51,200,000  [N x 512]
    unsigned int*   cw      = (unsigned int*)(ws + 51200000);    //  3,200,000  packed (wgt<<16|src)
    int*            row_ptr = (int*)(ws + 54400000);             //    200,064
    int*            cursor  = (int*)(ws + 54600064);             //    200,064
    unsigned short* Bt1     = (unsigned short*)(ws + 54800128);  //    131,072
    unsigned short* Bt2     = (unsigned short*)(ws + 54931200);  //    262,144
    unsigned short* Bt3     = (unsigned short*)(ws + 55193344);  //     65,536
    float*          b1      = (float*)(ws + 55258880);           //      1,024
    float*          b2      = (float*)(ws + 55259904);           //      1,024
    float*          b3      = (float*)(ws + 55260928);           //        256
    int*            flags   = (int*)(ws + 55261184);             //         64
    int*            bsum    = (int*)(ws + 55261248);             //      1,024
    unsigned short* x0bf    = (unsigned short*)(ws + 55262272);  // 12,800,000
    const size_t NEED_FULL   = 68062272;
    const size_t NEED_NOCONV = 55262272;

    if (ws_size < NEED_NOCONV) {
        long n = (long)N_NODES * OUTC;
        zout_kernel<<<(int)((n + 255) / 256), 256, 0, stream>>>((unsigned short*)d_out, n);
        return;
    }
    int do_conv = (ws_size >= NEED_FULL) ? 1 : 0;

    int* flagF = flags + 0;
    int* flagI = flags + 1;

    init_kernel<<<CURBLK + 2, 256, 0, stream>>>(cursor, (const unsigned int*)x0, flags, ei);

    int cb = do_conv ? ((N_NODES * IN_CH + 255) / 256) : 0;  // 25000
    const unsigned short* x0b = do_conv ? x0bf : (const unsigned short*)x0;
    {
        int ptotal = 256 * 256 + 256 * 512 + 64 * 512 + 256 + 256 + 64;
        int pblocks = (ptotal + 255) / 256;  // 899
        prep_all_kernel<<<cb + pblocks, 256, 0, stream>>>(x0, cb, w1r, w1x, w2r, w2x, lw,
                                                          b1h, b2h, lbh, flagF, x0bf,
                                                          Bt1, Bt2, Bt3, b1, b2, b3);
    }

    // CSR build
    int eblocks = (N_EDGES + 255) / 256;
    int nblk = (N_NODES + 255) / 256;  // 196
    hist_kernel<<<eblocks, 256, 0, stream>>>(ei, flagI, cursor);
    scanA_kernel<<<nblk, 256, 0, stream>>>(cursor, row_ptr, bsum);
    scanC_kernel<<<nblk, 256, 0, stream>>>(row_ptr, bsum, cursor, nblk);
    fill_kernel<<<eblocks, 256, 0, stream>>>(ei, ew, flagI, flagF, cursor, cw);

    int mblocks = (N_NODES + 63) / 64;   // 782
    int ablocks = (N_NODES + 3) / 4;     // 12500

    // layer 1: agg1 -> X12 cols 256..383; gemm1: [agg1|x0] @ Bt1 -> x1 (cols 0..255)
    agg1_kernel<<<ablocks, 256, 0, stream>>>(x0b, row_ptr, cw, X12);
    gemm_kernel<8><<<dim3(mblocks, 1), 256, 0, stream>>>(X12 + 256, 512, 128,
                                                         x0b, IN_CH, Bt1, 256, b1,
                                                         X12, 512, 0, N_NODES, 256, 1, flagF, 0);
    // layer 2: agg2 -> X12 cols 256..511; gemm2: [agg2|x1] @ Bt2 -> x2 (cols 256..511, per-row overwrite)
    agg2_kernel<<<ablocks, 256, 0, stream>>>(row_ptr, cw, X12);
    gemm_kernel<8><<<dim3(mblocks, 1), 256, 0, stream>>>(X12 + 256, 512, 256,
                                                         X12, 512, Bt2, 512, b2,
                                                         X12, 512, 256, N_NODES, 256, 1, flagF, 0);
    // head: [x1|x2] @ Bt3 -> out
    gemm_kernel<2><<<dim3(mblocks, 1), 256, 0, stream>>>(X12 + 256, 512, 0,
                                                         X12, 512, Bt3, 512, b3,
                                                         d_out, OUTC, 0, N_NODES, OUTC, 0, flagF, 1);
}

// Round 12
// 369.229 us; speedup vs baseline: 1.2652x; 1.0114x over previous
//
#include <hip/hip_runtime.h>
#include <hip/hip_bf16.h>

#define N_NODES 50000
#define N_EDGES 800000
#define IN_CH   128
#define HID     256
#define OUTC    51

typedef __attribute__((ext_vector_type(8))) short  bf16x8;
typedef __attribute__((ext_vector_type(4))) float  f32x4;
typedef __attribute__((ext_vector_type(4))) unsigned int u32x4;

__device__ __forceinline__ float bf2f(unsigned short u) {
    union { unsigned int i; float f; } v; v.i = ((unsigned int)u) << 16; return v.f;
}
__device__ __forceinline__ unsigned short f2bf(float f) {
    union { float f; unsigned int i; } v; v.f = f;
    unsigned int u = v.i;
    unsigned int r = (u + 0x7fffu + ((u >> 16) & 1u)) >> 16;  // RNE
    return (unsigned short)r;
}
__device__ __forceinline__ unsigned short ldbf(const void* p, long i, int isf) {
    return isf ? f2bf(((const float*)p)[i]) : ((const unsigned short*)p)[i];
}
__device__ __forceinline__ float ldf(const void* p, long i, int isf) {
    return isf ? ((const float*)p)[i] : bf2f(((const unsigned short*)p)[i]);
}
__device__ __forceinline__ void load_edge_nt(const int* __restrict__ ei, int e, int is64,
                                             int* src, int* dst) {
    if (is64) { *src = __builtin_nontemporal_load(ei + 2 * e);
                *dst = __builtin_nontemporal_load(ei + 2 * (N_EDGES + e)); }
    else      { *src = __builtin_nontemporal_load(ei + e);
                *dst = __builtin_nontemporal_load(ei + N_EDGES + e); }
}

#define CURBLK 196  // blocks to zero cursor[50001]

// ---------------- init: zero cursor + dtype probe + int64 detect ----------------
__global__ __launch_bounds__(256) void init_kernel(int* __restrict__ cursor,
                                                   const unsigned int* __restrict__ x0w, int* __restrict__ flags,
                                                   const int* __restrict__ ei) {
    int b = blockIdx.x;
    int tid = threadIdx.x;
    if (b < CURBLK) {
        int t = b * 256 + tid;
        if (t < N_NODES + 1) cursor[t] = 0;
        return;
    }
    if (b == CURBLK) {
        if (tid < 64) {
            unsigned int w = x0w[tid];
            unsigned int ex = (w >> 7) & 0xFFu;
            unsigned long long bm = __ballot(ex >= 0x60u && ex <= 0x90u);
            if (tid == 0) flags[0] = (__popcll(bm) >= 48) ? 0 : 1;
        }
        return;
    }
    // int64 detect -> flags[1]: 2048 strided samples of odd words; all-zero => int64
    __shared__ int any;
    if (tid == 0) any = 0;
    __syncthreads();
    int acc = 0;
    for (int s = 0; s < 8; s++) {
        int i = (tid * 8 + s) * (N_EDGES / 2048);
        acc |= ei[2 * i + 1];
    }
    if (acc != 0) any = 1;
    __syncthreads();
    if (tid == 0) flags[1] = any;
}

// ---------------- prep_all: x0 convert (cb blocks) + weight prep (899) + hist (3125) ----------------
__global__ void prep_all_kernel(const void* __restrict__ x0, int cb,
                                const void* __restrict__ w1r, const void* __restrict__ w1x,
                                const void* __restrict__ w2r, const void* __restrict__ w2x,
                                const void* __restrict__ lw,
                                const void* __restrict__ b1h, const void* __restrict__ b2h,
                                const void* __restrict__ lbh, const int* __restrict__ flags,
                                unsigned short* __restrict__ x0bf,
                                unsigned short* __restrict__ Bt1, unsigned short* __restrict__ Bt2,
                                unsigned short* __restrict__ Bt3,
                                float* __restrict__ b1, float* __restrict__ b2, float* __restrict__ b3,
                                const int* __restrict__ ei, int* __restrict__ cnt, int pblocks) {
    int isf = flags[0];
    if ((int)blockIdx.x < cb) {
        long t = (long)blockIdx.x * 256 + threadIdx.x;
        if (t < (long)N_NODES * IN_CH) x0bf[t] = ldbf(x0, t, isf);
        return;
    }
    int t = (blockIdx.x - cb) * 256 + threadIdx.x;
    if (t < 256 * 256) {
        int n = t >> 8, k = t & 255;
        Bt1[n * 256 + k] = (k < 128) ? ldbf(w1r, k * 256 + n, isf) : ldbf(w1x, (k - 128) * 256 + n, isf);
        return;
    }
    t -= 256 * 256;
    if (t < 256 * 512) {
        int n = t >> 9, k = t & 511;
        Bt2[n * 512 + k] = (k < 256) ? ldbf(w2r, k * 256 + n, isf) : ldbf(w2x, (k - 256) * 256 + n, isf);
        return;
    }
    t -= 256 * 512;
    if (t < 64 * 512) {
        int n = t >> 9, k = t & 511;
        Bt3[n * 512 + k] = (n < OUTC) ? ldbf(lw, k * OUTC + n, isf) : (unsigned short)0;
        return;
    }
    t -= 64 * 512;
    if (t < 256) { b1[t] = ldf(b1h, t, isf); return; }
    t -= 256;
    if (t < 256) { b2[t] = ldf(b2h, t, isf); return; }
    t -= 256;
    if (t < 64)  { b3[t] = (t < OUTC) ? ldf(lbh, t, isf) : 0.0f; return; }
    // ---- histogram blocks ----
    // UNSIGNED guard: leftover threads of the last prep block produce e<0 (r11 crash)
    int e = (blockIdx.x - cb - pblocks) * 256 + threadIdx.x;
    if ((unsigned)e >= (unsigned)N_EDGES) return;
    int is64 = (flags[1] == 0);
    int src, dst; load_edge_nt(ei, e, is64, &src, &dst);
    if ((unsigned)src >= N_NODES || (unsigned)dst >= N_NODES) return;
    atomicAdd(&cnt[dst], 1);
}

// ---------------- scan A: per-block exclusive + block sums ----------------
__global__ __launch_bounds__(256) void scanA_kernel(const int* __restrict__ cnt, int* __restrict__ rp,
                                                    int* __restrict__ bsum) {
    __shared__ int sd[256];
    int tid = threadIdx.x;
    int i = blockIdx.x * 256 + tid;
    int v = (i < N_NODES) ? cnt[i] : 0;
    sd[tid] = v;
    __syncthreads();
    for (int off = 1; off < 256; off <<= 1) {
        int t = (tid >= off) ? sd[tid - off] : 0;
        __syncthreads();
        sd[tid] += t;
        __syncthreads();
    }
    if (i < N_NODES) rp[i] = sd[tid] - v;
    if (tid == 255) bsum[blockIdx.x] = sd[255];
}
// ---------------- scan C: re-scan bsum locally, apply prefix ----------------
__global__ __launch_bounds__(256) void scanC_kernel(int* __restrict__ rp, const int* __restrict__ bsum,
                                                    int* __restrict__ cursor, int nB) {
    __shared__ int sd[256];
    int tid = threadIdx.x;
    int v = (tid < nB) ? bsum[tid] : 0;
    sd[tid] = v;
    __syncthreads();
    for (int off = 1; off < 256; off <<= 1) {
        int t = (tid >= off) ? sd[tid - off] : 0;
        __syncthreads();
        sd[tid] += t;
        __syncthreads();
    }
    int pfx = (blockIdx.x > 0) ? sd[blockIdx.x - 1] : 0;
    int i = blockIdx.x * 256 + tid;
    if (i < N_NODES) {
        int val = rp[i] + pfx;
        rp[i] = val;
        cursor[i] = val;
    }
    if (blockIdx.x == 0 && tid == 0) rp[N_NODES] = sd[255];
}

// ---------------- CSR: fill — one packed 4B record per edge ----------------
__global__ __launch_bounds__(256) void fill_kernel(const int* __restrict__ ei, const void* __restrict__ ew,
                                                   const int* __restrict__ flagI, const int* __restrict__ flagF,
                                                   int* __restrict__ cursor, unsigned int* __restrict__ cw) {
    int e = blockIdx.x * 256 + threadIdx.x;
    if (e >= N_EDGES) return;
    int is64 = (*flagI == 0);
    int src, dst; load_edge_nt(ei, e, is64, &src, &dst);
    if ((unsigned)src >= N_NODES || (unsigned)dst >= N_NODES) return;
    int pos = atomicAdd(&cursor[dst], 1);
    if ((unsigned)pos < N_EDGES)
        cw[pos] = ((unsigned int)ldbf(ew, e, *flagF) << 16) | (unsigned int)src;
}

// ---------------- fallback: zero output ----------------
__global__ __launch_bounds__(256) void zout_kernel(unsigned short* __restrict__ out, long n) {
    long t = (long)blockIdx.x * 256 + threadIdx.x;
    if (t < n) out[t] = 0;
}

// ---------------- agg1: 32 lanes/node x 8B (uint2), 2 nodes/wave ----------------
// X12[r][256+c] = bf16(sum_j w_j * x0[src_j][c]), c<128
__global__ __launch_bounds__(256) void agg1_kernel(const unsigned short* __restrict__ x0b,
                                                   const int* __restrict__ rp, const unsigned int* __restrict__ cw,
                                                   unsigned short* __restrict__ X12) {
    int r = blockIdx.x * 8 + (threadIdx.x >> 5);
    if (r >= N_NODES) return;
    int l = threadIdx.x & 31;            // lane in 32-group; channels l*4..l*4+3
    int grpbase = threadIdx.x & 32;      // group base within the 64-lane wave
    int js = rp[r], je = rp[r + 1];
    if (js < 0) js = 0;
    if (je > N_EDGES) je = N_EDGES;
    const uint2* xw = (const uint2*)x0b; // 32 uint2 per row
    float a0 = 0.f, a1 = 0.f, a2 = 0.f, a3 = 0.f;
    for (int base = js; base < je; base += 32) {
        int n = je - base; if (n > 32) n = 32;
        int idx = base + l; if (idx >= je) idx = je - 1;
        unsigned int rec = __builtin_nontemporal_load(cw + idx);
        for (int j = 0; j < n; j += 8) {
            int m = n - j; if (m > 8) m = 8;
            unsigned int vv[8]; uint2 q[8];
#pragma unroll
            for (int u = 0; u < 8; u++) vv[u] = __shfl(rec, grpbase + j + u);
#pragma unroll
            for (int u = 0; u < 8; u++) if (u < m)
                q[u] = xw[(long)(vv[u] & 0xFFFFu) * 32 + l];
#pragma unroll
            for (int u = 0; u < 8; u++) if (u < m) {
                float w = bf2f((unsigned short)(vv[u] >> 16));
                a0 += w * bf2f((unsigned short)(q[u].x & 0xffffu));
                a1 += w * bf2f((unsigned short)(q[u].x >> 16));
                a2 += w * bf2f((unsigned short)(q[u].y & 0xffffu));
                a3 += w * bf2f((unsigned short)(q[u].y >> 16));
            }
        }
    }
    uint2 pk;
    pk.x = (unsigned int)f2bf(a0) | ((unsigned int)f2bf(a1) << 16);
    pk.y = (unsigned int)f2bf(a2) | ((unsigned int)f2bf(a3) << 16);
    *(uint2*)&X12[(long)r * 512 + 256 + l * 4] = pk;
}

// ---------------- agg2: 32 lanes/node x 16B (uint4), 2 nodes/wave ----------------
// x1 = X12 cols 0..255; writes cols 256..511
__global__ __launch_bounds__(256) void agg2_kernel(const int* __restrict__ rp, const unsigned int* __restrict__ cw,
                                                   unsigned short* __restrict__ X12) {
    int r = blockIdx.x * 8 + (threadIdx.x >> 5);
    if (r >= N_NODES) return;
    int l = threadIdx.x & 31;            // channels l*8..l*8+7
    int grpbase = threadIdx.x & 32;
    int js = rp[r], je = rp[r + 1];
    if (js < 0) js = 0;
    if (je > N_EDGES) je = N_EDGES;
    float a0 = 0.f, a1 = 0.f, a2 = 0.f, a3 = 0.f;
    float a4 = 0.f, a5 = 0.f, a6 = 0.f, a7 = 0.f;
    for (int base = js; base < je; base += 32) {
        int n = je - base; if (n > 32) n = 32;
        int idx = base + l; if (idx >= je) idx = je - 1;
        unsigned int rec = __builtin_nontemporal_load(cw + idx);
        for (int j = 0; j < n; j += 8) {
            int m = n - j; if (m > 8) m = 8;
            unsigned int vv[8]; u32x4 q[8];
#pragma unroll
            for (int u = 0; u < 8; u++) vv[u] = __shfl(rec, grpbase + j + u);
#pragma unroll
            for (int u = 0; u < 8; u++) if (u < m)
                q[u] = *(const u32x4*)(X12 + (long)(vv[u] & 0xFFFFu) * 512 + l * 8);
#pragma unroll
            for (int u = 0; u < 8; u++) if (u < m) {
                float w = bf2f((unsigned short)(vv[u] >> 16));
                a0 += w * bf2f((unsigned short)(q[u][0] & 0xffffu));
                a1 += w * bf2f((unsigned short)(q[u][0] >> 16));
                a2 += w * bf2f((unsigned short)(q[u][1] & 0xffffu));
                a3 += w * bf2f((unsigned short)(q[u][1] >> 16));
                a4 += w * bf2f((unsigned short)(q[u][2] & 0xffffu));
                a5 += w * bf2f((unsigned short)(q[u][2] >> 16));
                a6 += w * bf2f((unsigned short)(q[u][3] & 0xffffu));
                a7 += w * bf2f((unsigned short)(q[u][3] >> 16));
            }
        }
    }
    u32x4 pk;
    pk[0] = (unsigned int)f2bf(a0) | ((unsigned int)f2bf(a1) << 16);
    pk[1] = (unsigned int)f2bf(a2) | ((unsigned int)f2bf(a3) << 16);
    pk[2] = (unsigned int)f2bf(a4) | ((unsigned int)f2bf(a5) << 16);
    pk[3] = (unsigned int)f2bf(a6) | ((unsigned int)f2bf(a7) << 16);
    *(u32x4*)&X12[(long)r * 512 + 256 + l * 8] = pk;
}

// ---------------- MFMA GEMM, full-width (grid y=1) -------------------
template<int TN>
__global__ __launch_bounds__(256) void gemm_kernel(
    const unsigned short* __restrict__ Aagg, int lda_agg, int Kagg,
    const unsigned short* __restrict__ Ax, int lda_x,
    const unsigned short* __restrict__ Bt, int K,
    const float* __restrict__ bias,
    void* __restrict__ out, int ldo, int ocol,
    int M, int realN, int do_relu, const int* __restrict__ flagF, int follow_dtype) {
    __shared__ __align__(16) unsigned short As[64][72];
    __shared__ __align__(16) unsigned short Bs[TN * 32][72];
    int tid = threadIdx.x;
    int bm0 = blockIdx.x * 64;
    int wave = tid >> 6, lane = tid & 63;
    int wm = wave >> 1, wn = wave & 1;
    int quad = lane >> 4, l16 = lane & 15;

    f32x4 acc[2][TN];
#pragma unroll
    for (int mt = 0; mt < 2; mt++)
#pragma unroll
        for (int nt = 0; nt < TN; nt++) acc[mt][nt] = (f32x4){0.f, 0.f, 0.f, 0.f};

    for (int k0 = 0; k0 < K; k0 += 64) {
        const unsigned short* srcp;
        int stride, koff;
        if (k0 < Kagg) { srcp = Aagg; stride = lda_agg; koff = k0; }
        else           { srcp = Ax;   stride = lda_x;   koff = k0 - Kagg; }
#pragma unroll
        for (int i = 0; i < 2; i++) {
            int c = tid + i * 256;
            int row = c >> 3, ko = (c & 7) * 8;
            int gr = bm0 + row;
            if (gr >= M) gr = M - 1;  // clamp: dup rows, writes guarded
            u32x4 v = *(const u32x4*)(srcp + (long)gr * stride + koff + ko);
            *(u32x4*)&As[row][ko] = v;
        }
#pragma unroll
        for (int p = 0; p < TN; p++) {
            int c = p * 256 + tid;
            int row = c >> 3, ko = (c & 7) * 8;
            u32x4 v = *(const u32x4*)(Bt + (long)row * K + k0 + ko);
            *(u32x4*)&Bs[row][ko] = v;
        }
        __syncthreads();
#pragma unroll
        for (int kc = 0; kc < 64; kc += 32) {
            bf16x8 a0 = *(const bf16x8*)&As[wm * 32 + l16][kc + quad * 8];
            bf16x8 a1 = *(const bf16x8*)&As[wm * 32 + 16 + l16][kc + quad * 8];
#pragma unroll
            for (int nt = 0; nt < TN; nt++) {
                bf16x8 b = *(const bf16x8*)&Bs[wn * (TN * 16) + nt * 16 + l16][kc + quad * 8];
                acc[0][nt] = __builtin_amdgcn_mfma_f32_16x16x32_bf16(a0, b, acc[0][nt], 0, 0, 0);
                acc[1][nt] = __builtin_amdgcn_mfma_f32_16x16x32_bf16(a1, b, acc[1][nt], 0, 0, 0);
            }
        }
        __syncthreads();
    }

    int out_f32 = follow_dtype ? (*flagF) : 0;
#pragma unroll
    for (int mt = 0; mt < 2; mt++) {
#pragma unroll
        for (int nt = 0; nt < TN; nt++) {
            f32x4 a = acc[mt][nt];
            int colI = wn * (TN * 16) + nt * 16 + l16;
            float bv = bias[colI];
#pragma unroll
            for (int r = 0; r < 4; r++) {
                int row = bm0 + wm * 32 + mt * 16 + quad * 4 + r;
                if (row < M && colI < realN) {
                    float v = a[r] + bv;
                    if (do_relu) v = v > 0.f ? v : 0.f;
                    long idx = (long)row * ldo + ocol + colI;
                    if (out_f32) ((float*)out)[idx] = v;
                    else ((unsigned short*)out)[idx] = f2bf(v);
                }
            }
        }
    }
}

extern "C" void kernel_launch(void* const* d_in, const int* in_sizes, int n_in,
                              void* d_out, int out_size, void* d_ws, size_t ws_size,
                              hipStream_t stream) {
    const void* x0  = d_in[0];
    const int*  ei  = (const int*)d_in[1];
    const void* ew  = d_in[2];
    const void* w1r = d_in[3];
    const void* b1h = d_in[4];
    const void* w1x = d_in[5];
    const void* w2r = d_in[6];
    const void* b2h = d_in[7];
    const void* w2x = d_in[8];
    const void* lw  = d_in[9];
    const void* lbh = d_in[10];

    // ---- workspace layout ----
    char* ws = (char*)d_ws;
    unsigned short* X12     = (unsigned short*)(ws);             // 51,200,000  [N x 512]
    unsigned int*   cw      = (unsigned int*)(ws + 51200000);    //  3,200,000  packed (wgt<<16|src)
    int*            row_ptr = (int*)(ws + 54400000);             //    200,064
    int*            cursor  = (int*)(ws + 54600064);             //    200,064
    unsigned short* Bt1     = (unsigned short*)(ws + 54800128);  //    131,072
    unsigned short* Bt2     = (unsigned short*)(ws + 54931200);  //    262,144
    unsigned short* Bt3     = (unsigned short*)(ws + 55193344);  //     65,536
    float*          b1      = (float*)(ws + 55258880);           //      1,024
    float*          b2      = (float*)(ws + 55259904);           //      1,024
    float*          b3      = (float*)(ws + 55260928);           //        256
    int*            flags   = (int*)(ws + 55261184);             //         64
    int*            bsum    = (int*)(ws + 55261248);             //      1,024
    unsigned short* x0bf    = (unsigned short*)(ws + 55262272);  // 12,800,000
    const size_t NEED_FULL   = 68062272;
    const size_t NEED_NOCONV = 55262272;

    if (ws_size < NEED_NOCONV) {
        long n = (long)N_NODES * OUTC;
        zout_kernel<<<(int)((n + 255) / 256), 256, 0, stream>>>((unsigned short*)d_out, n);
        return;
    }
    int do_conv = (ws_size >= NEED_FULL) ? 1 : 0;

    int* flagF = flags + 0;
    int* flagI = flags + 1;

    init_kernel<<<CURBLK + 2, 256, 0, stream>>>(cursor, (const unsigned int*)x0, flags, ei);

    int eblocks = (N_EDGES + 255) / 256;  // 3125
    int cb = do_conv ? ((N_NODES * IN_CH + 255) / 256) : 0;  // 25000
    const unsigned short* x0b = do_conv ? x0bf : (const unsigned short*)x0;
    {
        int ptotal = 256 * 256 + 256 * 512 + 64 * 512 + 256 + 256 + 64;
        int pblocks = (ptotal + 255) / 256;  // 899
        prep_all_kernel<<<cb + pblocks + eblocks, 256, 0, stream>>>(
            x0, cb, w1r, w1x, w2r, w2x, lw, b1h, b2h, lbh, flags, x0bf,
            Bt1, Bt2, Bt3, b1, b2, b3, ei, cursor, pblocks);
    }

    // CSR build
    int nblk = (N_NODES + 255) / 256;  // 196
    scanA_kernel<<<nblk, 256, 0, stream>>>(cursor, row_ptr, bsum);
    scanC_kernel<<<nblk, 256, 0, stream>>>(row_ptr, bsum, cursor, nblk);
    fill_kernel<<<eblocks, 256, 0, stream>>>(ei, ew, flagI, flagF, cursor, cw);

    int mblocks = (N_NODES + 63) / 64;   // 782
    int ablocks = (N_NODES + 7) / 8;     // 6250

    // layer 1: agg1 -> X12 cols 256..383; gemm1: [agg1|x0] @ Bt1 -> x1 (cols 0..255)
    agg1_kernel<<<ablocks, 256, 0, stream>>>(x0b, row_ptr, cw, X12);
    gemm_kernel<8><<<dim3(mblocks, 1), 256, 0, stream>>>(X12 + 256, 512, 128,
                                                         x0b, IN_CH, Bt1, 256, b1,
                                                         X12, 512, 0, N_NODES, 256, 1, flagF, 0);
    // layer 2: agg2 -> X12 cols 256..511; gemm2: [agg2|x1] @ Bt2 -> x2 (cols 256..511, per-row overwrite)
    agg2_kernel<<<ablocks, 256, 0, stream>>>(row_ptr, cw, X12);
    gemm_kernel<8><<<dim3(mblocks, 1), 256, 0, stream>>>(X12 + 256, 512, 256,
                                                         X12, 512, Bt2, 512, b2,
                                                         X12, 512, 256, N_NODES, 256, 1, flagF, 0);
    // head: [x1|x2] @ Bt3 -> out
    gemm_kernel<2><<<dim3(mblocks, 1), 256, 0, stream>>>(X12 + 256, 512, 0,
                                                         X12, 512, Bt3, 512, b3,
                                                         d_out, OUTC, 0, N_NODES, OUTC, 0, flagF, 1);
}